// Round 3
// baseline (276.966 us; speedup 1.0000x reference)
//
#include <hip/hip_runtime.h>

#define BATCH 256
#define NIN   1152
#define NOUT  10
#define DDIM  16
#define KPT   9    // NIN / 128 capsules per thread (each thread owns a d-quad)
#define NBLK  512  // persistent blocks, 2 per CU
#define STEPS 5    // items per block: 2560 / 512

// R6: persistent blocks + register double-buffer prefetch.
// R3/R4/R5 all land at 42+-1 us vs a ~30 us read floor: load-then-compute
// convoy (HBM idles during every block's compute phase, ~12 us additive).
// Fix: each block processes STEPS items; at item-n start it issues the 9
// dwordx4 prefetch loads for item n+1 into the alternate register buffer,
// then computes item n -> memory streams under compute. Per-item compute
// phases are exactly R5's proven structure. s-loop fully unrolled so A/B
// parity is compile-time (no runtime-indexed reg arrays -> no scratch);
// r-loop kept rolled to bound code size. launch_bounds(512,4) caps VGPR
// at 128 (2 u-buffers = 72 + overhead ~ 100).
// Item map: XCD x = pb&7 owns bb in [32x, 32x+32); id = s*64 + (pb>>3),
// bb = 32x + id/10, oo = id%10 -> sibling oo's temporally adjacent, bijective.

__device__ __forceinline__ void route_item(
    const float4 (&u)[KPT], float4 (&unext)[KPT],
    const float* __restrict__ next_base, const bool do_prefetch,
    float* __restrict__ outp,
    float* bsh, float* wsh, float (*red)[DDIM], float* vsh,
    float* smax, float* ssum,
    const int t, const int q, const int g, const int wave, const int lane)
{
    // ---- issue next item's loads first; first use is next item's s-phase ----
    if (do_prefetch) {
#pragma unroll
        for (int k = 0; k < KPT; ++k) {
            const int i = g + 128 * k;
            unext[k] = *reinterpret_cast<const float4*>(next_base + (size_t)i * (NOUT * DDIM));
        }
    }

    for (int i = t; i < NIN; i += 512) bsh[i] = 0.0f;
    __syncthreads();

    float scale = 0.0f;
#pragma unroll 1
    for (int r = 0; r < 3; ++r) {
        // ---- softmax over n_in: max ----
        float m = -3.4e38f;
        for (int i = t; i < NIN; i += 512) m = fmaxf(m, bsh[i]);
        for (int off = 32; off >= 1; off >>= 1) m = fmaxf(m, __shfl_down(m, off));
        if (lane == 0) smax[wave] = m;
        __syncthreads();
        m = fmaxf(fmaxf(fmaxf(smax[0], smax[1]), fmaxf(smax[2], smax[3])),
                  fmaxf(fmaxf(smax[4], smax[5]), fmaxf(smax[6], smax[7])));

        // ---- w = exp(b - m), Z = sum w ----
        float z = 0.0f;
        for (int i = t; i < NIN; i += 512) {
            const float w = __expf(bsh[i] - m);
            wsh[i] = w;
            z += w;
        }
        for (int off = 32; off >= 1; off >>= 1) z += __shfl_down(z, off);
        if (lane == 0) ssum[wave] = z;
        __syncthreads();
        const float invZ = 1.0f / (((ssum[0] + ssum[1]) + (ssum[2] + ssum[3])) +
                                   ((ssum[4] + ssum[5]) + (ssum[6] + ssum[7])));

        // ---- s_d = (1/Z) * sum_i w_i * u[i][d] ----
        float sx = 0.f, sy = 0.f, sz = 0.f, sw = 0.f;
#pragma unroll
        for (int k = 0; k < KPT; ++k) {
            const float w = wsh[g + 128 * k];
            sx += w * u[k].x; sy += w * u[k].y; sz += w * u[k].z; sw += w * u[k].w;
        }
        // reduce across the 16 g-groups of this wave (strides multiple of 4 keep q fixed)
        for (int off = 32; off >= 4; off >>= 1) {
            sx += __shfl_down(sx, off);
            sy += __shfl_down(sy, off);
            sz += __shfl_down(sz, off);
            sw += __shfl_down(sw, off);
        }
        if (lane < 4) {
            float* rp = &red[wave][lane * 4];
            rp[0] = sx; rp[1] = sy; rp[2] = sz; rp[3] = sw;
        }
        __syncthreads();
        if (t < DDIM) {
            vsh[t] = (((red[0][t] + red[1][t]) + (red[2][t] + red[3][t])) +
                      ((red[4][t] + red[5][t]) + (red[6][t] + red[7][t]))) * invZ;
        }
        __syncthreads();

        // ---- squash scale (redundant per-thread scalar math, broadcast reads);
        //      deferred to use sites (identical rounding, fewer barriers) ----
        float sqr = 0.0f;
#pragma unroll
        for (int d = 0; d < DDIM; ++d) { const float sv = vsh[d]; sqr += sv * sv; }
        scale = sqr / ((1.0f + sqr) * sqrtf(sqr + 1e-7f));

        if (r == 2) break;

        // ---- agreement a_i = sum_d u[i][d]*v_d ; b_i += a_i ----
        const float vx = vsh[q * 4 + 0] * scale, vy = vsh[q * 4 + 1] * scale;
        const float vz = vsh[q * 4 + 2] * scale, vw = vsh[q * 4 + 3] * scale;
#pragma unroll
        for (int k = 0; k < KPT; ++k) {
            float a = u[k].x * vx + u[k].y * vy + u[k].z * vz + u[k].w * vw;
            a += __shfl_xor(a, 1);
            a += __shfl_xor(a, 2);
            if (q == 0) bsh[g + 128 * k] += a;
        }
        __syncthreads();
    }

    if (t < DDIM) {
        outp[t] = vsh[t] * scale;
    }
    // NOTE: no trailing barrier needed. All bsh/wsh reads of this item are
    // upstream of the vsh-write barrier; the next item's post-zero barrier
    // separates its wsh/vsh writes from this item's reads.
}

__global__ __launch_bounds__(512, 4)
void routing_kernel(const float* __restrict__ u_hat, float* __restrict__ out) {
    __shared__ float bsh[NIN];
    __shared__ float wsh[NIN];
    __shared__ float red[8][DDIM];
    __shared__ float vsh[DDIM];
    __shared__ float smax[8];
    __shared__ float ssum[8];

    const int t    = threadIdx.x;
    const int q    = t & 3;
    const int g    = t >> 2;          // 0..127
    const int wave = t >> 6;
    const int lane = t & 63;

    const int pb    = blockIdx.x;
    const int x     = pb & 7;         // XCD (round-robin dispatch heuristic)
    const int local = pb >> 3;        // 0..63

    // item s -> (bb, oo)
    auto ubase = [&](int s) -> const float* {
        const int id = s * 64 + local;     // 0..319
        const int bb = x * 32 + id / 10;
        const int oo = id % 10;
        return u_hat + (size_t)bb * (NIN * NOUT * DDIM) + oo * DDIM + q * 4;
    };
    auto obase = [&](int s) -> float* {
        const int id = s * 64 + local;
        const int bb = x * 32 + id / 10;
        const int oo = id % 10;
        return out + (size_t)(bb * NOUT + oo) * DDIM;
    };

    float4 uA[KPT], uB[KPT];

    // preload item 0 (no overlap available for the very first load burst)
    {
        const float* base = ubase(0);
#pragma unroll
        for (int k = 0; k < KPT; ++k) {
            const int i = g + 128 * k;
            uA[k] = *reinterpret_cast<const float4*>(base + (size_t)i * (NOUT * DDIM));
        }
    }

#pragma unroll
    for (int s = 0; s < STEPS; ++s) {
        const bool pf = (s + 1 < STEPS);
        const float* nb = pf ? ubase(s + 1) : nullptr;
        float* op = obase(s);
        if (s & 1) route_item(uB, uA, nb, pf, op, bsh, wsh, red, vsh, smax, ssum,
                              t, q, g, wave, lane);
        else       route_item(uA, uB, nb, pf, op, bsh, wsh, red, vsh, smax, ssum,
                              t, q, g, wave, lane);
    }
}

extern "C" void kernel_launch(void* const* d_in, const int* in_sizes, int n_in,
                              void* d_out, int out_size, void* d_ws, size_t ws_size,
                              hipStream_t stream) {
    const float* u_hat = (const float*)d_in[0];
    float* out = (float*)d_out;
    routing_kernel<<<dim3(NBLK), dim3(512), 0, stream>>>(u_hat, out);
}